// Round 10
// baseline (647.772 us; speedup 1.0000x reference)
//
#include <hip/hip_runtime.h>

// Problem constants: B=2, t=5, C=16, G=64
#define G3_    (64 * 64 * 64)          // 262144
#define CCH    16
#define TT     5
#define NWARP  65536                    // gather blocks: 8 pose * 16 ch * 64 z * 8 y-oct
#define NCOPY  8192
#define NBLK   (NWARP + NCOPY)          // 73728 = 9 * 8192 = 8 * 9216

// ---------------------------------------------------------------------------
// Round-10: DIRECT CACHE GATHER — the LDS tile is deleted.
//
// Elimination complete through r9: TLP was the only lever that moved time
// (r3, r9), and it is now exhausted (occ 82-84% ~ wave cap; NCHB=1 would
// saturate VALU with duplicated setup). VALU instr count (r7), LDS instr
// count (r8), prefetch depth (r8), occupancy-via-regcap (r1) all neutral.
// Meanwhile FETCH=66MB vs 268MB algorithmic read: inputs are L2/L3-RESIDENT.
// => The LDS staging (and its whole barrier chain) is overhead for data the
// cache already serves (learn_hip common-mistake #7; attn V-staging removal
// was +26%). This kernel reads the 8 trilinear corners DIRECTLY from global:
//   - no LDS, no barriers, no staging, no zero-init, no bbox: blocks are
//     fully independent; stalls covered by wave TLP, not block pipelining.
//   - per-corner clamped indices + per-axis validity-masked weights =
//     exactly the reference semantics (no low-edge weight-swap needed).
//   - block = (pose, channel, gz, y-octet) -> 512 x-major outputs; thread
//     owns an x-adjacent pair, stores one aligned float2.
//   - pose-channel-major block order + XCD-contiguous swizzle: each 1MB
//     (pose,channel) input volume stays L2-resident for its 512 blocks.
// Verification signature: SQ_LDS_BANK_CONFLICT must drop 12.9M -> ~0.
// Kept: hoisted coeff kernel; copy interleave (8 gather : 1 copy).
// ---------------------------------------------------------------------------

// Setup kernel: per pose n -> {ax,bx,cx, ay,by,cy, az,bz,cz, kx,ky,kz}.
__global__ void coeff_kernel(const float* __restrict__ cam, float* __restrict__ Tc)
{
    int n = threadIdx.x;
    if (n >= 8) return;
    int b = n >> 2, j = n & 3;
    const float* p0 = cam + (size_t)(b * TT) * 16;
    const float* p1 = cam + (size_t)(b * TT + j + 1) * 16;
    float a00 = p0[0], a01 = p0[1], a02 = p0[2],  at0 = p0[3];
    float a10 = p0[4], a11 = p0[5], a12 = p0[6],  at1 = p0[7];
    float a20 = p0[8], a21 = p0[9], a22 = p0[10], at2 = p0[11];
    float b00 = p1[0], b01 = p1[1], b02 = p1[2],  bt0 = p1[3];
    float b10 = p1[4], b11 = p1[5], b12 = p1[6],  bt1 = p1[7];
    float b20 = p1[8], b21 = p1[9], b22 = p1[10], bt2 = p1[11];
    // T = P0 * inv(P1), rigid: R = R0*R1^T, tr = t0 - R*t1.
    float R00 = a00*b00 + a01*b01 + a02*b02;
    float R01 = a00*b10 + a01*b11 + a02*b12;
    float R02 = a00*b20 + a01*b21 + a02*b22;
    float R10 = a10*b00 + a11*b01 + a12*b02;
    float R11 = a10*b10 + a11*b11 + a12*b12;
    float R12 = a10*b20 + a11*b21 + a12*b22;
    float R20 = a20*b00 + a21*b01 + a22*b02;
    float R21 = a20*b10 + a21*b11 + a22*b12;
    float R22 = a20*b20 + a21*b21 + a22*b22;
    float trx = at0 - (R00*bt0 + R01*bt1 + R02*bt2);
    float try_= at1 - (R10*bt0 + R11*bt1 + R12*bt2);
    float trz = at2 - (R20*bt0 + R21*bt1 + R22*bt2);

    const float S  = 1.0f / 64.0f;
    const float SC = 32.0f / 0.4921875f;
    float ax = SC * R00 * S, bx = SC * R01 * S, cx = SC * R02 * S;
    float ay = SC * R10 * S, by = SC * R11 * S, cy = SC * R12 * S;
    float az = SC * R20 * S, bz = SC * R21 * S, cz = SC * R22 * S;
    float* o = Tc + n * 12;
    o[0] = ax; o[1] = bx; o[2] = cx;
    o[3] = ay; o[4] = by; o[5] = cy;
    o[6] = az; o[7] = bz; o[8] = cz;
    o[9]  = -31.5f * (ax + bx + cx) + SC * trx + 31.5f;
    o[10] = -31.5f * (ay + by + cy) + SC * try_ + 31.5f;
    o[11] = -31.5f * (az + bz + cz) + SC * trz + 31.5f;
}

__global__ __launch_bounds__(256) void fused_kernel(const float* __restrict__ vox,
                                                    const float* __restrict__ Tc,
                                                    float* __restrict__ out)
{
    const int tid = threadIdx.x;

    // XCD-contiguous bijective swizzle (73728 % 8 == 0).
    const int bid  = blockIdx.x;
    const int sbid = (bid & 7) * (NBLK / 8) + (bid >> 3);
    const int q9   = sbid / 9;
    const int r9   = sbid - q9 * 9;

    if (r9 == 8) {
        // ---- copy block: out[:,0] = voxels[:,0] ----
        int t4 = q9 * 256 + tid;                        // [0, 2^21)
        int b  = t4 >> 20;
        int rr = t4 & ((1 << 20) - 1);
        size_t base = (size_t)(b * TT) * CCH * G3_;
        const float4* s = (const float4*)(vox + base);
        float4* d = (float4*)(out + base);
        d[rr] = s[rr];
        return;
    }

    // ---- gather block: (pose, channel, gz, y-octet), 512 x-major outputs ----
    const int wid = q9 * 8 + r9;                        // [0, 65536)
    const int pc  = wid >> 9;                           // pose-channel [0,128)
    const int rem = wid & 511;
    const int gz  = rem >> 3;                           // [0,64)
    const int gy  = ((rem & 7) << 3) + (tid >> 5);      // [0,64)
    const int gx0 = (tid & 31) << 1;                    // even, [0,62]
    const int n   = pc >> 4;                            // pose [0,8)
    const int c   = pc & 15;                            // channel [0,16)
    const int b   = n >> 2, j = n & 3;

    // precomputed affine coefficients (block-uniform -> SGPR)
    const float* Cp = Tc + n * 12;
    const float ax = Cp[0], bx = Cp[1], cx = Cp[2];
    const float ay = Cp[3], by = Cp[4], cy = Cp[5];
    const float az = Cp[6], bz = Cp[7], cz = Cp[8];
    const float kx = Cp[9], ky = Cp[10], kz = Cp[11];

    const size_t fb = ((size_t)(b * TT + j + 1) * CCH + c) * G3_;
    const float* v = vox + fb;

    // sample position for output (gx0, gy, gz); second output at gx0+1 is
    // derived incrementally (+ax,+ay,+az).
    float ix = kx + ax * gx0 + bx * gy + cx * gz;
    float iy = ky + ay * gx0 + by * gy + cy * gz;
    float iz = kz + az * gx0 + bz * gy + cz * gz;

    float res[2];
    #pragma unroll
    for (int k = 0; k < 2; ++k) {
        if (k) { ix += ax; iy += ay; iz += az; }
        float fx = floorf(ix), fy = floorf(iy), fz = floorf(iz);
        float tx = ix - fx, ty = iy - fy, tz = iz - fz;
        int X0 = (int)fx, Y0 = (int)fy, Z0 = (int)fz;

        // per-axis weights with validity mask (== reference corner masking)
        float wx0 = ((unsigned)X0       < 64u) ? (1.0f - tx) : 0.0f;
        float wx1 = ((unsigned)(X0 + 1) < 64u) ? tx          : 0.0f;
        float wy0 = ((unsigned)Y0       < 64u) ? (1.0f - ty) : 0.0f;
        float wy1 = ((unsigned)(Y0 + 1) < 64u) ? ty          : 0.0f;
        float wz0 = ((unsigned)Z0       < 64u) ? (1.0f - tz) : 0.0f;
        float wz1 = ((unsigned)(Z0 + 1) < 64u) ? tz          : 0.0f;

        // clamped corner indices (invalid axes contribute weight 0; the
        // clamped read returns a finite in-volume value)
        int xc0 = min(max(X0,     0), 63), xc1 = min(max(X0 + 1, 0), 63);
        int yc0 = min(max(Y0,     0), 63), yc1 = min(max(Y0 + 1, 0), 63);
        int zc0 = min(max(Z0,     0), 63), zc1 = min(max(Z0 + 1, 0), 63);

        int zy00 = (zc0 << 12) + (yc0 << 6);
        int zy01 = (zc0 << 12) + (yc1 << 6);
        int zy10 = (zc1 << 12) + (yc0 << 6);
        int zy11 = (zc1 << 12) + (yc1 << 6);

        float v000 = v[zy00 + xc0], v001 = v[zy00 + xc1];
        float v010 = v[zy01 + xc0], v011 = v[zy01 + xc1];
        float v100 = v[zy10 + xc0], v101 = v[zy10 + xc1];
        float v110 = v[zy11 + xc0], v111 = v[zy11 + xc1];

        float t00 = v000 * wx0 + v001 * wx1;
        float t01 = v010 * wx0 + v011 * wx1;
        float t10 = v100 * wx0 + v101 * wx1;
        float t11 = v110 * wx0 + v111 * wx1;
        float u0  = t00 * wy0 + t01 * wy1;
        float u1  = t10 * wy0 + t11 * wy1;
        res[k] = u0 * wz0 + u1 * wz1;
    }

    float* o = out + fb + ((gz << 12) + (gy << 6) + gx0);
    *(float2*)o = make_float2(res[0], res[1]);
}

extern "C" void kernel_launch(void* const* d_in, const int* in_sizes, int n_in,
                              void* d_out, int out_size, void* d_ws, size_t ws_size,
                              hipStream_t stream)
{
    const float* vox = (const float*)d_in[0];
    const float* cam = (const float*)d_in[1];
    float* out = (float*)d_out;
    float* Tc  = (float*)d_ws;          // 8 poses * 12 floats

    hipLaunchKernelGGL(coeff_kernel, dim3(1), dim3(64), 0, stream, cam, Tc);
    hipLaunchKernelGGL(fused_kernel, dim3(NBLK), dim3(256), 0, stream, vox, Tc, out);
}

// Round 11
// 339.334 us; speedup vs baseline: 1.9090x; 1.9090x over previous
//
#include <hip/hip_runtime.h>

// Problem constants: B=2, t=5, C=16, G=64
#define G3_    (64 * 64 * 64)          // 262144
#define CCH    16
#define TT     5
#define LSTRIDE 17                      // padded LDS x-stride (cols 0..16)
#define BUF    4096                     // floats: single LDS buffer (max idx 3841)
#define NWARP  65536                    // 16 channels * 4096 tiles (NCHB=1)
#define NCOPY  8192
#define NBLK   (NWARP + NCOPY)          // 73728 = 9 * 8192, % 8 == 0

// ---------------------------------------------------------------------------
// Round-11: revert r10's direct gather (458us: L1 address-divergence tax --
// LDS was the divergence absorber, keep it). Continue the ONLY proven lever
// (chain-shortening + block TLP; r3 +27%, r9 +8%) to its endpoint: NCHB=1.
//   - chain per block: stage -> ONE barrier -> interp -> store. No handoff,
//     no ds-write-after-read hazard, no prefetch. 65536 warp blocks (2x r9).
//   - affordable because the per-(pose,tile) BBOX is hoisted to a 4096-entry
//     packed-uint table (bbox is channel-invariant; NCHB=1 would otherwise
//     recompute it 16x). Per-channel VALU ~195 vs r9's 160 (x1.22 -> ~73%
//     busy), leaving headroom for the time drop.
//   - ws_size guarded on host; fallback template computes bbox in-kernel.
// Kept from r9: x-pair outputs + fused float2 store, ds_read2 corner reads
// ({0,1},{17,18}) + low-edge weight swap, even-aligned float2 staging,
// minimal zero-init (r8 proof), hoisted coeff kernel, XCD swizzle,
// 8 warp : 1 copy interleave, NO launch_bounds min-waves (r1: spill).
// ---------------------------------------------------------------------------

// Setup kernel 1: per pose n -> {ax,bx,cx, ay,by,cy, az,bz,cz, kx,ky,kz}.
__global__ void coeff_kernel(const float* __restrict__ cam, float* __restrict__ Tc)
{
    int n = threadIdx.x;
    if (n >= 8) return;
    int b = n >> 2, j = n & 3;
    const float* p0 = cam + (size_t)(b * TT) * 16;
    const float* p1 = cam + (size_t)(b * TT + j + 1) * 16;
    float a00 = p0[0], a01 = p0[1], a02 = p0[2],  at0 = p0[3];
    float a10 = p0[4], a11 = p0[5], a12 = p0[6],  at1 = p0[7];
    float a20 = p0[8], a21 = p0[9], a22 = p0[10], at2 = p0[11];
    float b00 = p1[0], b01 = p1[1], b02 = p1[2],  bt0 = p1[3];
    float b10 = p1[4], b11 = p1[5], b12 = p1[6],  bt1 = p1[7];
    float b20 = p1[8], b21 = p1[9], b22 = p1[10], bt2 = p1[11];
    // T = P0 * inv(P1), rigid: R = R0*R1^T, tr = t0 - R*t1.
    float R00 = a00*b00 + a01*b01 + a02*b02;
    float R01 = a00*b10 + a01*b11 + a02*b12;
    float R02 = a00*b20 + a01*b21 + a02*b22;
    float R10 = a10*b00 + a11*b01 + a12*b02;
    float R11 = a10*b10 + a11*b11 + a12*b12;
    float R12 = a10*b20 + a11*b21 + a12*b22;
    float R20 = a20*b00 + a21*b01 + a22*b02;
    float R21 = a20*b10 + a21*b11 + a22*b12;
    float R22 = a20*b20 + a21*b21 + a22*b22;
    float trx = at0 - (R00*bt0 + R01*bt1 + R02*bt2);
    float try_= at1 - (R10*bt0 + R11*bt1 + R12*bt2);
    float trz = at2 - (R20*bt0 + R21*bt1 + R22*bt2);

    const float S  = 1.0f / 64.0f;
    const float SC = 32.0f / 0.4921875f;
    float ax = SC * R00 * S, bx = SC * R01 * S, cx = SC * R02 * S;
    float ay = SC * R10 * S, by = SC * R11 * S, cy = SC * R12 * S;
    float az = SC * R20 * S, bz = SC * R21 * S, cz = SC * R22 * S;
    float* o = Tc + n * 12;
    o[0] = ax; o[1] = bx; o[2] = cx;
    o[3] = ay; o[4] = by; o[5] = cy;
    o[6] = az; o[7] = bz; o[8] = cz;
    o[9]  = -31.5f * (ax + bx + cx) + SC * trx + 31.5f;
    o[10] = -31.5f * (ay + by + cy) + SC * try_ + 31.5f;
    o[11] = -31.5f * (az + bz + cz) + SC * trz + 31.5f;
}

// Bbox helper (shared by table kernel and fallback path).
__device__ __forceinline__ void tile_bbox(const float* Cp, int ox, int oy, int oz,
                                          int& xlo_e, int& ylo, int& zlo,
                                          int& sxe, int& sy, int& sz)
{
    const float ax = Cp[0], bx = Cp[1], cx = Cp[2];
    const float ay = Cp[3], by = Cp[4], cy = Cp[5];
    const float az = Cp[6], bz = Cp[7], cz = Cp[8];
    const float kx = Cp[9], ky = Cp[10], kz = Cp[11];

    float x0a = ax * ox, x0b = ax * (ox + 7);
    float x1a = bx * oy, x1b = bx * (oy + 7);
    float x2a = cx * oz, x2b = cx * (oz + 7);
    float min_ix = kx + fminf(x0a, x0b) + fminf(x1a, x1b) + fminf(x2a, x2b);
    float max_ix = kx + fmaxf(x0a, x0b) + fmaxf(x1a, x1b) + fmaxf(x2a, x2b);
    float y0a = ay * ox, y0b = ay * (ox + 7);
    float y1a = by * oy, y1b = by * (oy + 7);
    float y2a = cy * oz, y2b = cy * (oz + 7);
    float min_iy = ky + fminf(y0a, y0b) + fminf(y1a, y1b) + fminf(y2a, y2b);
    float max_iy = ky + fmaxf(y0a, y0b) + fmaxf(y1a, y1b) + fmaxf(y2a, y2b);
    float z0a = az * ox, z0b = az * (ox + 7);
    float z1a = bz * oy, z1b = bz * (oy + 7);
    float z2a = cz * oz, z2b = cz * (oz + 7);
    float min_iz = kz + fminf(z0a, z0b) + fminf(z1a, z1b) + fminf(z2a, z2b);
    float max_iz = kz + fmaxf(z0a, z0b) + fmaxf(z1a, z1b) + fmaxf(z2a, z2b);

    int xlo = min(max((int)floorf(min_ix), 0), 63);
    int xhi = min(max((int)floorf(max_ix) + 1, 0), 63);
    ylo     = min(max((int)floorf(min_iy), 0), 63);
    int yhi = min(max((int)floorf(max_iy) + 1, 0), 63);
    zlo     = min(max((int)floorf(min_iz), 0), 63);
    int zhi = min(max((int)floorf(max_iz) + 1, 0), 63);
    xlo_e = xlo & ~1;                    // even-align for float2 staging
    sxe   = xhi - xlo_e + 1;             // <= 16
    sy    = yhi - ylo + 1;               // <= 15
    sz    = zhi - zlo + 1;               // <= 15
}

// Setup kernel 2: per (pose,tile) t9 -> packed bbox uint.
// pack: xlo_e[5:0] | ylo[11:6] | zlo[17:12] | sxe[22:18] | sy[26:23] | sz[30:27]
__global__ void bbox_kernel(const float* __restrict__ Tc, unsigned* __restrict__ Bb)
{
    int t9 = blockIdx.x * 256 + threadIdx.x;
    if (t9 >= 4096) return;
    int n  = t9 >> 9;
    int t6 = t9 & 511;
    int ox = (t6 & 7) << 3, oy = ((t6 >> 3) & 7) << 3, oz = (t6 >> 6) << 3;
    int xlo_e, ylo, zlo, sxe, sy, sz;
    tile_bbox(Tc + n * 12, ox, oy, oz, xlo_e, ylo, zlo, sxe, sy, sz);
    Bb[t9] = (unsigned)xlo_e | ((unsigned)ylo << 6) | ((unsigned)zlo << 12)
           | ((unsigned)sxe << 18) | ((unsigned)sy << 23) | ((unsigned)sz << 27);
}

template<bool TBL>
__global__ __launch_bounds__(256) void fused_kernel(const float* __restrict__ vox,
                                                    const float* __restrict__ Tc,
                                                    const unsigned* __restrict__ Bb,
                                                    float* __restrict__ out)
{
    __shared__ float lds[BUF];                          // 16 KB
    const int tid = threadIdx.x;

    // XCD-contiguous bijective swizzle (73728 % 8 == 0).
    const int bid  = blockIdx.x;
    const int sbid = (bid & 7) * (NBLK / 8) + (bid >> 3);
    const int q9   = sbid / 9;
    const int r9   = sbid - q9 * 9;

    if (r9 == 8) {
        // ---- copy block: out[:,0] = voxels[:,0] ----
        int t4 = q9 * 256 + tid;                        // [0, 2^21)
        int b  = t4 >> 20;
        int rr = t4 & ((1 << 20) - 1);
        size_t base = (size_t)(b * TT) * CCH * G3_;
        const float4* s = (const float4*)(vox + base);
        float4* d = (float4*)(out + base);
        d[rr] = s[rr];
        return;
    }

    // ---- warp block: ONE channel of one 8^3 tile ----
    const int wid = q9 * 8 + r9;                        // [0, 65536)
    const int cg  = wid >> 12;                          // channel [0,16)
    const int t9  = wid & 4095;                         // (pose,tile) id
    const int n   = t9 >> 9;                            // pose [0,8)
    const int t6  = t9 & 511;
    const int ox  = (t6 & 7) << 3;
    const int oy  = ((t6 >> 3) & 7) << 3;
    const int oz  = (t6 >> 6) << 3;
    const int b   = n >> 2, j = n & 3;

    // coefficients (block-uniform)
    const float* Cp = Tc + n * 12;
    const float ax = Cp[0], bx = Cp[1], cx = Cp[2];
    const float ay = Cp[3], by = Cp[4], cy = Cp[5];
    const float az = Cp[6], bz = Cp[7], cz = Cp[8];
    const float kx = Cp[9], ky = Cp[10], kz = Cp[11];

    // bbox: from table (packed uint) or computed (fallback)
    int xlo_e, ylo, zlo, sxe, sy, sz;
    if (TBL) {
        unsigned u = Bb[t9];
        xlo_e = u & 63;
        ylo   = (u >> 6) & 63;
        zlo   = (u >> 12) & 63;
        sxe   = (u >> 18) & 31;
        sy    = (u >> 23) & 15;
        sz    = (u >> 27) & 15;
    } else {
        tile_bbox(Cp, ox, oy, oz, xlo_e, ylo, zlo, sxe, sy, sz);
    }
    const int xhi   = xlo_e + sxe - 1;
    const int lstep = sy * LSTRIDE;

    // per-thread interp setup. Thread owns the x-adjacent output pair
    // (gx0, gx0+1): 2nd sample pos = 1st + (ax,ay,az).
    const int gx0 = ox + ((tid & 3) << 1);
    const int gy  = oy + ((tid >> 2) & 7);
    const int gz  = oz + (tid >> 5);
    const float ix0 = kx + ax * gx0 + bx * gy + cx * gz;
    const float iy0 = ky + ay * gx0 + by * gy + cy * gz;
    const float iz0 = kz + az * gx0 + bz * gy + cz * gz;

    float wx0[2], wx1[2], wy0[2], wy1[2], wz0[2], wz1[2];
    int base0[2], base1[2];
    #pragma unroll
    for (int k = 0; k < 2; ++k) {
        float ix = ix0 + (k ? ax : 0.0f);
        float iy = iy0 + (k ? ay : 0.0f);
        float iz = iz0 + (k ? az : 0.0f);
        float fx = floorf(ix), fy = floorf(iy), fz = floorf(iz);
        float tx = ix - fx, ty = iy - fy, tz = iz - fz;
        int X0 = (int)fx, Y0 = (int)fy, Z0 = (int)fz;

        float w0 = ((unsigned)X0 < 64u) ? (1.0f - tx) : 0.0f;
        float w1 = ((unsigned)(X0 + 1) < 64u) ? tx : 0.0f;
        int rxu = X0 - xlo_e;
        // X0==-1: low corner invalid, high valid at col 0 -> swap weights.
        wx0[k] = (rxu < 0) ? w1 : w0;
        wx1[k] = (rxu < 0) ? 0.0f : w1;
        int rx0 = min(max(rxu, 0), sxe - 1);

        w0 = ((unsigned)Y0 < 64u) ? (1.0f - ty) : 0.0f;
        w1 = ((unsigned)(Y0 + 1) < 64u) ? ty : 0.0f;
        int ryu = Y0 - ylo;
        wy0[k] = (ryu < 0) ? w1 : w0;
        wy1[k] = (ryu < 0) ? 0.0f : w1;
        int ry0 = min(max(ryu, 0), sy - 1);

        wz0[k] = ((unsigned)Z0 < 64u) ? (1.0f - tz) : 0.0f;
        wz1[k] = ((unsigned)(Z0 + 1) < 64u) ? tz : 0.0f;
        int rz0 = min(max(Z0     - zlo, 0), sz - 1);
        int rz1 = min(max(Z0 + 1 - zlo, 0), sz - 1);

        base0[k] = rz0 * lstep + ry0 * LSTRIDE + rx0;   // + {0,1,17,18}
        base1[k] = rz1 * lstep + ry0 * LSTRIDE + rx0;
    }
    const int soff = (gz << 12) + (gy << 6) + gx0;      // float2-aligned

    const size_t fb = ((size_t)(b * TT + j + 1) * CCH + cg) * G3_;
    const float* vbase = vox + fb;

    // staging: 8 even x-pairs (float2) x 16 y-rows; z split across the two
    // half-blocks (zh). xe even <= 62 -> xe+1 <= 63: never leaves row.
    const int lane8 = tid & 7;
    const int row16 = (tid >> 3) & 15;
    const int zh    = tid >> 7;                         // 0/1
    const int xe    = xlo_e + (lane8 << 1);
    const bool actS = (xe <= xhi) && (row16 < sy);
    const int grow  = (zlo << 12) + ((ylo + row16) << 6) + xe;
    const int lrow  = row16 * LSTRIDE + (lane8 << 1);

    float2 stg[8];

    // prologue = whole chain: issue loads, minimal zero-init under the load
    // latency, write, ONE barrier.
    if (actS) {
        const float2* gp = (const float2*)(vbase + grow);
        #pragma unroll
        for (int k = 0; k < 8; ++k) {
            int zz = (k << 1) + zh;
            if (zz < sz) stg[k] = gp[(size_t)zz << 11];
        }
    }
    // MINIMAL zero-init (r8 proof): only weight-0-reachable unstaged slots —
    // col sxe of each staged row + the 17-float tail after the last z-slab.
    // Benign finite/finite race with staging at col sxe (read at weight 0).
    {
        int rz = tid >> 4, ry = tid & 15;
        if (rz < sz && ry < sy) lds[rz * lstep + ry * LSTRIDE + sxe] = 0.0f;
        if (tid < 17) lds[sz * lstep + tid] = 0.0f;
    }
    if (actS) {
        #pragma unroll
        for (int k = 0; k < 8; ++k) {
            int zz = (k << 1) + zh;
            if (zz < sz) {
                float* wp = lds + lrow + zz * lstep;
                wp[0] = stg[k].x;
                wp[1] = stg[k].y;
            }
        }
    }
    __syncthreads();

    // interp: 4x ds_read2_b32 per output, one fused float2 store.
    float* op = out + fb;
    float res[2];
    #pragma unroll
    for (int k = 0; k < 2; ++k) {
        const float* pz0 = lds + base0[k];
        const float* pz1 = lds + base1[k];
        float v000 = pz0[0],  v001 = pz0[1];
        float v010 = pz0[17], v011 = pz0[18];
        float v100 = pz1[0],  v101 = pz1[1];
        float v110 = pz1[17], v111 = pz1[18];
        float t00 = v000 * wx0[k] + v001 * wx1[k];
        float t01 = v010 * wx0[k] + v011 * wx1[k];
        float t10 = v100 * wx0[k] + v101 * wx1[k];
        float t11 = v110 * wx0[k] + v111 * wx1[k];
        float u0  = t00 * wy0[k] + t01 * wy1[k];
        float u1  = t10 * wy0[k] + t11 * wy1[k];
        res[k] = u0 * wz0[k] + u1 * wz1[k];
    }
    *(float2*)(op + soff) = make_float2(res[0], res[1]);
}

extern "C" void kernel_launch(void* const* d_in, const int* in_sizes, int n_in,
                              void* d_out, int out_size, void* d_ws, size_t ws_size,
                              hipStream_t stream)
{
    const float* vox = (const float*)d_in[0];
    const float* cam = (const float*)d_in[1];
    float* out = (float*)d_out;
    float* Tc  = (float*)d_ws;                     // 96 floats (8 poses * 12)
    unsigned* Bb = (unsigned*)((char*)d_ws + 512); // 4096 packed bboxes (16 KB)

    hipLaunchKernelGGL(coeff_kernel, dim3(1), dim3(64), 0, stream, cam, Tc);
    if (ws_size >= 512 + 4096 * sizeof(unsigned)) {
        hipLaunchKernelGGL(bbox_kernel, dim3(16), dim3(256), 0, stream, Tc, Bb);
        hipLaunchKernelGGL((fused_kernel<true>), dim3(NBLK), dim3(256), 0, stream,
                           vox, Tc, Bb, out);
    } else {
        hipLaunchKernelGGL((fused_kernel<false>), dim3(NBLK), dim3(256), 0, stream,
                           vox, Tc, (const unsigned*)nullptr, out);
    }
}